// Round 8
// baseline (2208.992 us; speedup 1.0000x reference)
//
#include <hip/hip_runtime.h>
#include <math.h>

#define BB 4
#define NP 8192
#define CF 64
#define MQ 2048
#define KS 32

// ---- workspace layout (float indices) ----
#define WS_FT     0u         // ft: [B][N][64] transposed features (2097152 floats)
#define WS_NIDX   2097152u   // nidx: [B][M][K] int (262144)
#define WS_IDXI   2359296u   // idx int copy: [B][M] (8192)
#define WS_ST1    2367488u   // stats1 slices: [64][2][64] (8192)
#define WS_ST2    2375680u   // stats2 slices: [64][2][128] (16384)
#define WS_SC1    2392064u   // scale/shift bn1: [2][64] (128)
#define WS_SC2    2392192u   // scale/shift bn2: [2][128] (256)
#define WS_MAXY2  2392448u   // maxy2: [B*M][128] (1048576)
#define WS_W1P    3441024u   // padded w1: [64][68] (4352)

typedef float v2f __attribute__((ext_vector_type(2)));
typedef unsigned long long u64;

// ------------------------------------------------------------------
// transpose f [B][64][N] -> ft [B][N][64]
// ------------------------------------------------------------------
__global__ __launch_bounds__(256) void transpose_f_kernel(
    const float* __restrict__ f, float* __restrict__ ft) {
  __shared__ float tile[64][65];
  int b = blockIdx.y;
  int n0 = blockIdx.x * 64;
  int cc = threadIdx.x >> 6;   // 0..3
  int nn = threadIdx.x & 63;
  #pragma unroll
  for (int r = 0; r < 16; ++r) {
    int c = cc * 16 + r;
    tile[c][nn] = f[((size_t)b * 64 + c) * NP + n0 + nn];
  }
  __syncthreads();
  #pragma unroll
  for (int r = 0; r < 16; ++r) {
    int nl = cc * 16 + r;
    ft[((size_t)b * NP + n0 + nl) * 64 + nn] = tile[nn][nl];
  }
}

// ------------------------------------------------------------------
// pad w1 [64][67] -> w1p [64][68] (last col 0), 16B-aligned rows
// ------------------------------------------------------------------
__global__ void prep_w1_kernel(const float* __restrict__ w1, float* __restrict__ w1p) {
  int i = blockIdx.x * 256 + threadIdx.x;
  if (i < 64 * 68) {
    int o = i / 68, c = i % 68;
    w1p[i] = (c < 67) ? w1[o * 67 + c] : 0.0f;
  }
}

// ------------------------------------------------------------------
// FPS v7: spatially-sorted + exact bbox pruning, DETERMINISTIC sort.
// r7 lesson: atomicAdd-ordered scatter made point->thread assignment
// vary per launch -> graph-replay tripwire failure. v7 scatter is
// wave-serialized (8 barrier-phases); within a wave, equal-cell lanes
// find each other via 9 ballots, rank by lower-lane popcount, and only
// the leader lane atomicAdds (one atomic per distinct cell per step ->
// no same-address races -> returned bases deterministic). Assignment
// is now a fixed function of the input.
// Pruning: thread skips its rescan iff lb(pivot,bbox)^2 * 0.999 >=
// its current max dmin (conservative by ~1000x the rn rounding bound;
// skipping provably leaves every dmin and the cached key unchanged).
// Scan math byte-identical to r2-r6 (rn sub/mul/add + min, contract
// off). Per-slot u64 key (f32bits(dm)<<32 | ~origidx): global max =
// largest dmin, ties -> smallest original index (numpy argmax
// first-occurrence), exact under any assignment. DPP wave-max ->
// lane63 ds atomicMax into triple-buffered slot, 1 barrier/iter,
// no global ops in the loop, bulk coalesced epilogue.
// ------------------------------------------------------------------
#define FPS_T 512
#define SLOTS 16

template <int CTRL>
__device__ __forceinline__ u64 dpp_max_step(u64 k) {
  int lo = (int)(unsigned)k;
  int hi = (int)(unsigned)(k >> 32);
  int slo = __builtin_amdgcn_update_dpp(0, lo, CTRL, 0xF, 0xF, true);
  int shi = __builtin_amdgcn_update_dpp(0, hi, CTRL, 0xF, 0xF, true);
  u64 s = ((u64)(unsigned)shi << 32) | (u64)(unsigned)slo;
  return s > k ? s : k;
}

__global__ __launch_bounds__(512, 1) void fps_kernel(
    const float* __restrict__ p, float* __restrict__ out, int* __restrict__ idx_i) {
#pragma clang fp contract(off)
  __shared__ float4 sp4[NP];                 // 128 KB
  __shared__ int win[MQ];                    // 8 KB (doubles as sort scratch)
  __shared__ u64 cnd[3];
  int b = blockIdx.x;
  const float* pb = p + (size_t)b * NP * 3;
  float* out_newp = out;                               // [B][M][3]
  float* out_idxf = out + BB*MQ*3 + (size_t)BB*128*MQ; // [B][M] as float
  int t = threadIdx.x;
  int lane = t & 63;
  int wv = t >> 6;

  // ---- Phase A: load 16 points, histogram by 9-bit morton cell ----
  float tx[SLOTS], ty[SLOTS], tz[SLOTS];
  int cells[SLOTS];
  win[t] = 0;                                // hist region win[0..512)
  __syncthreads();
  #pragma unroll
  for (int s = 0; s < SLOTS; ++s) {
    int i = s * FPS_T + t;
    float x = pb[i*3+0], y = pb[i*3+1], z = pb[i*3+2];
    tx[s] = x; ty[s] = y; tz[s] = z;
    int cx = (int)(x * 8.0f); cx = cx < 0 ? 0 : (cx > 7 ? 7 : cx);
    int cy = (int)(y * 8.0f); cy = cy < 0 ? 0 : (cy > 7 ? 7 : cy);
    int cz = (int)(z * 8.0f); cz = cz < 0 ? 0 : (cz > 7 ? 7 : cz);
    int mx = (cx & 1) | ((cx & 2) << 2) | ((cx & 4) << 4);
    int my = (cy & 1) | ((cy & 2) << 2) | ((cy & 4) << 4);
    int mz = (cz & 1) | ((cz & 2) << 2) | ((cz & 4) << 4);
    int cell = mx | (my << 1) | (mz << 2);   // 9-bit morton, [0,512)
    cells[s] = cell;
    atomicAdd(&win[cell], 1);                // SUM: order-independent
  }
  __syncthreads();
  // ---- Phase B: exclusive prefix sum over 512 cells (deterministic) ----
  {
    int myCnt = win[t];
    int* sA = win; int* sB = win + 512;
    __syncthreads();                 // everyone read their count
    bool a2b = true;
    for (int off = 1; off < 512; off <<= 1) {
      int* src = a2b ? sA : sB; int* dst = a2b ? sB : sA;
      int v = src[t];
      if (t >= off) v += src[t - off];
      dst[t] = v;
      a2b = !a2b;
      __syncthreads();
    }
    int incl = sB[t];                // 9 steps -> final in sB
    __syncthreads();
    win[t] = incl - myCnt;           // exclusive base -> running offset
  }
  __syncthreads();
  // ---- Phase C: DETERMINISTIC scatter, wave-serialized ----
  // Within the active wave: eq-mask of identical cells via 9 ballots;
  // rank = popcount of lower equal lanes; leader lane (lowest) does the
  // single atomicAdd per distinct cell. No same-address atomic races
  // anywhere -> positions are a fixed function of the input.
  for (int w = 0; w < 8; ++w) {
    if (wv == w) {
      #pragma unroll
      for (int s = 0; s < SLOTS; ++s) {
        int c = cells[s];
        u64 eq = ~0ull;
        #pragma unroll
        for (int bit = 0; bit < 9; ++bit) {
          u64 bset = __ballot(((c >> bit) & 1) != 0);
          eq &= (((c >> bit) & 1) ? bset : ~bset);
        }
        int rank = (int)__popcll(eq & ((1ull << lane) - 1ull));
        int leader = (int)__builtin_ctzll(eq);
        int base = 0;
        if (lane == leader) base = atomicAdd(&win[c], (int)__popcll(eq));
        base = __shfl(base, leader);
        sp4[base + rank] = make_float4(tx[s], ty[s], tz[s],
                                       __int_as_float(s * FPS_T + t));
      }
    }
    __syncthreads();
  }
  // ---- Phase D: read my sorted segment + bbox ----
  unsigned notI[SLOTS];
  float bminx = INFINITY, bminy = INFINITY, bminz = INFINITY;
  float bmaxx = -INFINITY, bmaxy = -INFINITY, bmaxz = -INFINITY;
  #pragma unroll
  for (int s = 0; s < SLOTS; ++s) {
    float4 q = sp4[t * SLOTS + s];
    tx[s] = q.x; ty[s] = q.y; tz[s] = q.z;
    notI[s] = ~(unsigned)__float_as_int(q.w);
    bminx = fminf(bminx, q.x); bmaxx = fmaxf(bmaxx, q.x);
    bminy = fminf(bminy, q.y); bmaxy = fmaxf(bmaxy, q.y);
    bminz = fminf(bminz, q.z); bmaxz = fmaxf(bmaxz, q.z);
  }
  __syncthreads();
  // ---- Phase E: rewrite sp4 as ORIG-indexed coords ----
  #pragma unroll
  for (int s = 0; s < SLOTS; ++s) {
    int oi = (int)(~notI[s]);
    sp4[oi] = make_float4(tx[s], ty[s], tz[s], 0.0f);
  }
  if (t < 3) cnd[t] = 0ull;
  if (t == 0) win[0] = 0;
  // pack registers as v2f pairs for the scan
  v2f px2[8], py2[8], pz2[8], dmin2[8];
  #pragma unroll
  for (int k = 0; k < 8; ++k) {
    px2[k] = (v2f){tx[2*k], tx[2*k+1]};
    py2[k] = (v2f){ty[2*k], ty[2*k+1]};
    pz2[k] = (v2f){tz[2*k], tz[2*k+1]};
    dmin2[k] = (v2f){INFINITY, INFINITY};
  }
  __syncthreads();
  float lx = sp4[0].x, ly = sp4[0].y, lz = sp4[0].z;

  float bvCache = INFINITY;      // current max dmin over my slots
  u64 cachedKey = 0ull;
  for (int j = 1; j < MQ; ++j) {
    // conservative skip: if lb^2*0.999 >= bvCache, no slot can change
    float dxm = fmaxf(fmaxf(bminx - lx, lx - bmaxx), 0.0f);
    float dym = fmaxf(fmaxf(bminy - ly, ly - bmaxy), 0.0f);
    float dzm = fmaxf(fmaxf(bminz - lz, lz - bmaxz), 0.0f);
    float lbsq = dxm*dxm + dym*dym + dzm*dzm;
    if (!(lbsq * 0.999f >= bvCache)) {
      v2f l2x = (v2f){lx, lx}, l2y = (v2f){ly, ly}, l2z = (v2f){lz, lz};
      u64 c0 = 0ull, c1 = 0ull;   // dual u64-key argmax chains
      #pragma unroll
      for (int k = 0; k < 8; ++k) {
        v2f dx = px2[k] - l2x;
        v2f dy = py2[k] - l2y;
        v2f dz = pz2[k] - l2z;
        v2f dd = ((dx*dx) + (dy*dy)) + (dz*dz);
        v2f dm = __builtin_elementwise_min(dmin2[k], dd);
        dmin2[k] = dm;
        u64 k0 = ((u64)__float_as_uint(dm.x) << 32) | (u64)notI[2*k];
        u64 k1 = ((u64)__float_as_uint(dm.y) << 32) | (u64)notI[2*k+1];
        c0 = k0 > c0 ? k0 : c0;
        c1 = k1 > c1 ? k1 : c1;
      }
      cachedKey = c0 > c1 ? c0 : c1;
      bvCache = __uint_as_float((unsigned)(cachedKey >> 32));
    }
    u64 key = cachedKey;
    // DPP wave-max: result lands in lane 63
    key = dpp_max_step<0x111>(key);  // row_shr:1
    key = dpp_max_step<0x112>(key);  // row_shr:2
    key = dpp_max_step<0x114>(key);  // row_shr:4
    key = dpp_max_step<0x118>(key);  // row_shr:8
    key = dpp_max_step<0x142>(key);  // row_bcast15
    key = dpp_max_step<0x143>(key);  // row_bcast31
    int slot = j % 3;
    if (lane == 63) atomicMax(&cnd[slot], key);
    __syncthreads();                 // lgkm-only drain (no global ops in loop)
    u64 kw = cnd[slot];
    if (t == 0) cnd[(j + 2) % 3] = 0ull;
    int wi = (int)(~(unsigned)kw);   // ORIGINAL index
    float4 c = sp4[wi];              // orig-indexed: one b128 broadcast
    lx = c.x; ly = c.y; lz = c.z;
    if (t == 0) win[j] = wi;
  }

  __syncthreads();
  // bulk coalesced epilogue
  #pragma unroll
  for (int k2 = 0; k2 < MQ / FPS_T; ++k2) {
    int j = k2 * FPS_T + t;
    int wi = win[j];
    out_idxf[b*MQ + j] = (float)wi;
    idx_i[b*MQ + j] = wi;
    float4 c = sp4[wi];
    float* np_ = &out_newp[(size_t)(b*MQ + j) * 3];
    np_[0] = c.x; np_[1] = c.y; np_[2] = c.z;
  }
}

// ------------------------------------------------------------------
// ball query: one wave per query. Mirrors |q|^2+|p|^2-2*dot with rn
// ops; threshold is float( double(0.1)*double(0.1) ).
// ------------------------------------------------------------------
__global__ __launch_bounds__(256) void ballq_kernel(
    const float* __restrict__ p, const float* __restrict__ newp,
    int* __restrict__ nidx) {
  int qid = blockIdx.x * 4 + (threadIdx.x >> 6);   // b*M+m
  int lane = threadIdx.x & 63;
  int b = qid >> 11;
  const float* pb = p + (size_t)b * NP * 3;
  float qx = newp[qid*3], qy = newp[qid*3+1], qz = newp[qid*3+2];
  float sq_q = __fadd_rn(__fadd_rn(__fmul_rn(qx,qx), __fmul_rn(qy,qy)), __fmul_rn(qz,qz));
  const float R2 = (float)(0.1 * 0.1);   // 0.009999999776482582f
  int found = 0, first = -1;
  int* outp = nidx + (size_t)qid * KS;
  for (int base = 0; base < NP; base += 64) {
    int n = base + lane;
    float x = pb[n*3], y = pb[n*3+1], z = pb[n*3+2];
    float sq_p = __fadd_rn(__fadd_rn(__fmul_rn(x,x), __fmul_rn(y,y)), __fmul_rn(z,z));
    float dot  = __fadd_rn(__fadd_rn(__fmul_rn(qx,x), __fmul_rn(qy,y)), __fmul_rn(qz,z));
    float d2   = __fadd_rn(__fadd_rn(sq_q, sq_p), __fmul_rn(-2.0f, dot));
    bool hit = d2 < R2;
    unsigned long long mask = __ballot(hit);
    if (mask) {
      if (first < 0) first = base + __builtin_ctzll(mask);
      int cnt = __popcll(mask);
      if (found < KS) {
        int rank = __popcll(mask & ((1ull << lane) - 1ull));
        if (hit && found + rank < KS) outp[found + rank] = n;
      }
      found += cnt;
      if (found >= KS) break;
    }
  }
  int fcl = found < KS ? found : KS;
  int padv = first < 0 ? 0 : first;
  if (lane >= fcl && lane < KS) outp[lane] = padv;
}

// ------------------------------------------------------------------
// P1: conv1 over gathered x, accumulate per-channel sum/sumsq.
// One wave per query, lane = output channel.
// ------------------------------------------------------------------
__global__ __launch_bounds__(256) void p1_kernel(
    const float* __restrict__ p, const float* __restrict__ newp,
    const float* __restrict__ ft, const int* __restrict__ nidx,
    const float* __restrict__ w1p, float* __restrict__ stats1) {
  __shared__ __align__(16) float xbuf[4][KS][68];
  __shared__ float wbs[4][64], wbq[4][64];
  int wv = threadIdx.x >> 6, lane = threadIdx.x & 63;
  int qid = blockIdx.x * 4 + wv;
  int b = qid >> 11;
  // gather x = [dp(3) | fj(64) | 0]
  int nv = (lane < KS) ? nidx[(size_t)qid * KS + lane] : 0;
  float qx = newp[qid*3], qy = newp[qid*3+1], qz = newp[qid*3+2];
  for (int kk = 0; kk < KS; ++kk) {
    int n = __shfl(nv, kk);
    const float* fr = ft + ((size_t)b * NP + n) * 64;
    xbuf[wv][kk][3 + lane] = fr[lane];
    if (lane < 3) {
      const float* pp = p + ((size_t)b * NP + n) * 3;
      float qc = (lane == 0) ? qx : ((lane == 1) ? qy : qz);
      xbuf[wv][kk][lane] = __fsub_rn(pp[lane], qc);
    }
    if (lane == 3) xbuf[wv][kk][67] = 0.0f;
  }
  __syncthreads();
  // conv1: lane = channel o; preload its w row into regs
  const float4* wr = (const float4*)(w1p + lane * 68);
  float4 wreg[17];
  #pragma unroll
  for (int c4 = 0; c4 < 17; ++c4) wreg[c4] = wr[c4];
  float ss = 0.f, qq = 0.f;
  for (int kk = 0; kk < KS; ++kk) {
    const float4* xr = (const float4*)(&xbuf[wv][kk][0]);
    float acc = 0.f;
    #pragma unroll
    for (int c4 = 0; c4 < 17; ++c4) {
      float4 w = wreg[c4]; float4 x = xr[c4];
      acc += w.x*x.x + w.y*x.y + w.z*x.z + w.w*x.w;
    }
    ss += acc; qq += acc * acc;
  }
  wbs[wv][lane] = ss; wbq[wv][lane] = qq;
  __syncthreads();
  if (threadIdx.x < 64) {
    float s  = wbs[0][threadIdx.x] + wbs[1][threadIdx.x] + wbs[2][threadIdx.x] + wbs[3][threadIdx.x];
    float s2 = wbq[0][threadIdx.x] + wbq[1][threadIdx.x] + wbq[2][threadIdx.x] + wbq[3][threadIdx.x];
    int slice = blockIdx.x & 63;
    atomicAdd(&stats1[(slice*2+0)*64 + threadIdx.x], s);
    atomicAdd(&stats1[(slice*2+1)*64 + threadIdx.x], s2);
  }
}

// ------------------------------------------------------------------
// finalize bn1 stats -> scale/shift
// ------------------------------------------------------------------
__global__ void fin1_kernel(const float* __restrict__ stats1,
                            const float* __restrict__ g, const float* __restrict__ bb,
                            float* __restrict__ sc) {
  int o = threadIdx.x;  // 64
  float s = 0.f, q = 0.f;
  for (int sl = 0; sl < 64; ++sl) { s += stats1[(sl*2+0)*64+o]; q += stats1[(sl*2+1)*64+o]; }
  const float cnt = (float)(BB * MQ * KS);
  float mean = s / cnt;
  float var = q / cnt - mean * mean;
  float rstd = 1.0f / sqrtf(var + 1e-5f);
  float gs = g[o] * rstd;
  sc[o] = gs;
  sc[64+o] = bb[o] - mean * gs;
}

__global__ void fin2_kernel(const float* __restrict__ stats2,
                            const float* __restrict__ g, const float* __restrict__ bb,
                            float* __restrict__ sc) {
  int o = threadIdx.x;  // 128
  float s = 0.f, q = 0.f;
  for (int sl = 0; sl < 64; ++sl) { s += stats2[(sl*2+0)*128+o]; q += stats2[(sl*2+1)*128+o]; }
  const float cnt = (float)(BB * MQ * KS);
  float mean = s / cnt;
  float var = q / cnt - mean * mean;
  float rstd = 1.0f / sqrtf(var + 1e-5f);
  float gs = g[o] * rstd;
  sc[o] = gs;
  sc[128+o] = bb[o] - mean * gs;
}

// ------------------------------------------------------------------
// P2: recompute conv1, bn1+relu (h overwrites x rows in LDS), conv2,
// per-channel stats2 + per-query max over K (bn2 commutes with max).
// ------------------------------------------------------------------
__global__ __launch_bounds__(256) void p2_kernel(
    const float* __restrict__ p, const float* __restrict__ newp,
    const float* __restrict__ ft, const int* __restrict__ nidx,
    const float* __restrict__ w1p, const float* __restrict__ w2,
    const float* __restrict__ sc1,
    float* __restrict__ stats2, float* __restrict__ maxy2) {
  __shared__ __align__(16) float xbuf[4][KS][68];
  __shared__ float wbs[4][128], wbq[4][128];
  int wv = threadIdx.x >> 6, lane = threadIdx.x & 63;
  int qid = blockIdx.x * 4 + wv;
  int b = qid >> 11;
  // gather
  int nv = (lane < KS) ? nidx[(size_t)qid * KS + lane] : 0;
  float qx = newp[qid*3], qy = newp[qid*3+1], qz = newp[qid*3+2];
  for (int kk = 0; kk < KS; ++kk) {
    int n = __shfl(nv, kk);
    const float* fr = ft + ((size_t)b * NP + n) * 64;
    xbuf[wv][kk][3 + lane] = fr[lane];
    if (lane < 3) {
      const float* pp = p + ((size_t)b * NP + n) * 3;
      float qc = (lane == 0) ? qx : ((lane == 1) ? qy : qz);
      xbuf[wv][kk][lane] = __fsub_rn(pp[lane], qc);
    }
    if (lane == 3) xbuf[wv][kk][67] = 0.0f;
  }
  __syncthreads();
  // conv1 + bn1 + relu; h[o=lane][kk] written into xbuf[wv][kk][lane]
  {
    const float4* wr = (const float4*)(w1p + lane * 68);
    float4 wreg[17];
    #pragma unroll
    for (int c4 = 0; c4 < 17; ++c4) wreg[c4] = wr[c4];
    float s1v = sc1[lane], t1v = sc1[64 + lane];
    for (int kk = 0; kk < KS; ++kk) {
      const float4* xr = (const float4*)(&xbuf[wv][kk][0]);
      float acc = 0.f;
      #pragma unroll
      for (int c4 = 0; c4 < 17; ++c4) {
        float4 w = wreg[c4]; float4 x = xr[c4];
        acc += w.x*x.x + w.y*x.y + w.z*x.z + w.w*x.w;
      }
      float h = fmaxf(0.0f, fmaf(acc, s1v, t1v));
      xbuf[wv][kk][lane] = h;   // safe: whole row kk consumed by all lanes (lockstep)
    }
  }
  // conv2: lane computes channels lane and lane+64
  const float4* w2a = (const float4*)(w2 + (size_t)lane * 64);
  const float4* w2b = (const float4*)(w2 + (size_t)(lane + 64) * 64);
  float4 wra[16], wrb[16];
  #pragma unroll
  for (int c4 = 0; c4 < 16; ++c4) { wra[c4] = w2a[c4]; wrb[c4] = w2b[c4]; }
  float ss0 = 0.f, qq0 = 0.f, mx0 = -INFINITY;
  float ss1 = 0.f, qq1 = 0.f, mx1 = -INFINITY;
  for (int kk = 0; kk < KS; ++kk) {
    const float4* hr = (const float4*)(&xbuf[wv][kk][0]);
    float a0 = 0.f, a1 = 0.f;
    #pragma unroll
    for (int c4 = 0; c4 < 16; ++c4) {
      float4 h4 = hr[c4];
      float4 wa = wra[c4]; float4 wb = wrb[c4];
      a0 += wa.x*h4.x + wa.y*h4.y + wa.z*h4.z + wa.w*h4.w;
      a1 += wb.x*h4.x + wb.y*h4.y + wb.z*h4.z + wb.w*h4.w;
    }
    ss0 += a0; qq0 += a0*a0; mx0 = fmaxf(mx0, a0);
    ss1 += a1; qq1 += a1*a1; mx1 = fmaxf(mx1, a1);
  }
  maxy2[(size_t)qid * 128 + lane] = mx0;
  maxy2[(size_t)qid * 128 + 64 + lane] = mx1;
  wbs[wv][lane] = ss0; wbs[wv][64+lane] = ss1;
  wbq[wv][lane] = qq0; wbq[wv][64+lane] = qq1;
  __syncthreads();
  if (threadIdx.x < 128) {
    float s  = wbs[0][threadIdx.x] + wbs[1][threadIdx.x] + wbs[2][threadIdx.x] + wbs[3][threadIdx.x];
    float s2 = wbq[0][threadIdx.x] + wbq[1][threadIdx.x] + wbq[2][threadIdx.x] + wbq[3][threadIdx.x];
    int slice = blockIdx.x & 63;
    atomicAdd(&stats2[(slice*2+0)*128 + threadIdx.x], s);
    atomicAdd(&stats2[(slice*2+1)*128 + threadIdx.x], s2);
  }
}

// ------------------------------------------------------------------
// P3: skip conv (w_skip · f[:,idx] + b_skip) + bn2 affine on max + relu
// ------------------------------------------------------------------
__global__ __launch_bounds__(256) void p3_kernel(
    const float* __restrict__ ft, const int* __restrict__ idx_i,
    const float* __restrict__ w_skip, const float* __restrict__ b_skip,
    const float* __restrict__ sc2, const float* __restrict__ maxy2,
    float* __restrict__ outf) {
  int wv = threadIdx.x >> 6, lane = threadIdx.x & 63;
  int qid = blockIdx.x * 4 + wv;
  int b = qid >> 11, m = qid & (MQ - 1);
  int n = idx_i[qid];
  const float4* f4 = (const float4*)(ft + ((size_t)b * NP + n) * 64);
  const float4* wa = (const float4*)(w_skip + (size_t)lane * 64);
  const float4* wb = (const float4*)(w_skip + (size_t)(lane + 64) * 64);
  float a0 = b_skip[lane], a1 = b_skip[lane + 64];
  #pragma unroll
  for (int c4 = 0; c4 < 16; ++c4) {
    float4 x = f4[c4]; float4 u = wa[c4]; float4 v = wb[c4];
    a0 += u.x*x.x + u.y*x.y + u.z*x.z + u.w*x.w;
    a1 += v.x*x.x + v.y*x.y + v.z*x.z + v.w*x.w;
  }
  float v0 = maxy2[(size_t)qid * 128 + lane];
  float v1 = maxy2[(size_t)qid * 128 + 64 + lane];
  float r0 = fmaxf(0.0f, fmaf(v0, sc2[lane],      sc2[128 + lane])      + a0);
  float r1 = fmaxf(0.0f, fmaf(v1, sc2[lane + 64], sc2[128 + lane + 64]) + a1);
  outf[((size_t)b * 128 + lane) * MQ + m] = r0;
  outf[((size_t)b * 128 + lane + 64) * MQ + m] = r1;
}

// ------------------------------------------------------------------
extern "C" void kernel_launch(void* const* d_in, const int* in_sizes, int n_in,
                              void* d_out, int out_size, void* d_ws, size_t ws_size,
                              hipStream_t stream) {
  (void)in_sizes; (void)n_in; (void)out_size; (void)ws_size;
  const float* p   = (const float*)d_in[0];
  const float* f   = (const float*)d_in[1];
  const float* w1  = (const float*)d_in[2];
  const float* g1  = (const float*)d_in[3];
  const float* b1  = (const float*)d_in[4];
  const float* w2  = (const float*)d_in[5];
  const float* g2  = (const float*)d_in[6];
  const float* b2  = (const float*)d_in[7];
  const float* wsk = (const float*)d_in[8];
  const float* bsk = (const float*)d_in[9];
  float* out = (float*)d_out;
  float* wsf = (float*)d_ws;

  float* ft    = wsf + WS_FT;
  int*   nidx  = (int*)(wsf + WS_NIDX);
  int*   idxi  = (int*)(wsf + WS_IDXI);
  float* st1   = wsf + WS_ST1;
  float* st2   = wsf + WS_ST2;
  float* sc1   = wsf + WS_SC1;
  float* sc2   = wsf + WS_SC2;
  float* maxy2 = wsf + WS_MAXY2;
  float* w1p   = wsf + WS_W1P;

  float* out_newp = out;
  float* out_f    = out + BB*MQ*3;

  // zero the atomic stats accumulators (st1+st2 are contiguous)
  (void)hipMemsetAsync(st1, 0, (8192 + 16384) * sizeof(float), stream);

  transpose_f_kernel<<<dim3(NP/64, BB), 256, 0, stream>>>(f, ft);
  prep_w1_kernel<<<17, 256, 0, stream>>>(w1, w1p);
  fps_kernel<<<BB, FPS_T, 0, stream>>>(p, out, idxi);
  ballq_kernel<<<BB*MQ/4, 256, 0, stream>>>(p, out_newp, nidx);
  p1_kernel<<<BB*MQ/4, 256, 0, stream>>>(p, out_newp, ft, nidx, w1p, st1);
  fin1_kernel<<<1, 64, 0, stream>>>(st1, g1, b1, sc1);
  p2_kernel<<<BB*MQ/4, 256, 0, stream>>>(p, out_newp, ft, nidx, w1p, w2, sc1, st2, maxy2);
  fin2_kernel<<<1, 128, 0, stream>>>(st2, g2, b2, sc2);
  p3_kernel<<<BB*MQ/4, 256, 0, stream>>>(ft, idxi, wsk, bsk, sc2, maxy2, out_f);
}